// Round 3
// baseline (325.246 us; speedup 1.0000x reference)
//
#include <hip/hip_runtime.h>
#include <hip/hip_bf16.h>
#include <hip/hip_fp16.h>
#include <math.h>

typedef _Float16 f16x8 __attribute__((ext_vector_type(8)));
typedef _Float16 h2 __attribute__((ext_vector_type(2)));
typedef __fp16 h2amd __attribute__((ext_vector_type(2)));   // builtin return type
typedef float f32x16 __attribute__((ext_vector_type(16)));
typedef float f32x2 __attribute__((ext_vector_type(2)));

#define DH 100      // hidden dim
#define G  4096     // table size per net
#define WSTR 120    // LDS row stride in f16 elems
#define NBLK 256    // grid size; capacity argument guarantees co-residency:
                    // __launch_bounds__(256,2) => VGPR<=256, LDS ~51KB < 80KB
                    // => every CU hosts >=2 blocks => capacity 512 >= 256.

// ws float offsets
#define WS_CCW   0      // [0,101)
#define WS_XSC   128    // [128,229)
#define WS_OH0   256    // 3
#define WS_EOH1  260    // 3
#define WS_P01   264    // NBLK min/max pairs (logits)  [264,776)
#define WS_RNG   800    // 3 nets x {u0, dlt, inv, pad} [800,812)
#define WS_BAR   960    // 4 ints: one-shot grid barrier counters
#define WS_TAB   17408  // 3*G table floats

__device__ __forceinline__ unsigned short f2bf(float f) {
    unsigned int u = __float_as_uint(f);
    unsigned int r = (u + 0x7FFFu + ((u >> 16) & 1u)) >> 16;  // RNE
    return (unsigned short)r;
}
__device__ __forceinline__ unsigned int hpk(float a, float b) {
    union { h2amd h; unsigned int u; } c;
    c.h = __builtin_amdgcn_cvt_pkrtz(a, b);
    return c.u;
}
__device__ __forceinline__ h2 hpk2(float a, float b) {
    union { h2amd ha; h2 h; } c;
    c.ha = __builtin_amdgcn_cvt_pkrtz(a, b);
    return c.h;
}

// one-shot grid barrier: device-scope atomics (coherent point), explicit
// release/acquire fences. Counters zeroed host-side per launch.
__device__ __forceinline__ void gridbar(int* bar, int idx) {
    __syncthreads();
    if (threadIdx.x == 0) {
        __threadfence();   // release: prior global writes visible agent-wide
        __hip_atomic_fetch_add(&bar[idx], 1, __ATOMIC_RELEASE, __HIP_MEMORY_SCOPE_AGENT);
        while (__hip_atomic_load(&bar[idx], __ATOMIC_ACQUIRE, __HIP_MEMORY_SCOPE_AGENT) < NBLK)
            __builtin_amdgcn_s_sleep(8);
        __threadfence();   // acquire: invalidate stale L1/L2 lines
    }
    __syncthreads();
}

union FR { f16x8 v; h2 h[4]; unsigned int u32[4]; };

// phase-overlaid LDS (max member ~49.8 KB)
union MegaSh {
    struct { float hw[DH * 101]; float bufA[128]; float bufB[128]; } prep;
    struct {
        __align__(16) _Float16 W1[DH * WSTR];
        __align__(16) _Float16 W2[DH * WSTR];
        unsigned int w0p[64], b0p[64], w3p[64];
        float g[256];
    } mlp;
    struct { __align__(16) float tab[3 * G]; } ev;
};

// R3-R11-verified transposed MFMA dataflow (lane^32 exchange, laundered LDS
// reads): evaluates g(u)=elu(MLP(u))+1 for the two 128-row groups. dzout[j]
// is valid on !hfb lanes.
__device__ __forceinline__ void mlp2(const _Float16* __restrict__ W1s,
                                     const _Float16* __restrict__ W2s,
                                     const unsigned int* __restrict__ w0p_s,
                                     const unsigned int* __restrict__ b0p_s,
                                     const unsigned int* __restrict__ w3p_s,
                                     const h2* uu, const int* wrow,
                                     const int hf, const bool hfb,
                                     const float b3, unsigned int zoff,
                                     float* dzout)
{
    const f32x2 zero2 = {0.f, 0.f};

    // layer 1: B-frags for both row groups, shared w0/b0 loads
    FR a1[2][7];
    #pragma unroll
    for (int ks = 0; ks < 7; ++ks) {
        int pb = ks * 8 + hf * 4 + zoff;
        uint4 wq = *(const uint4*)&w0p_s[pb];
        uint4 bq = *(const uint4*)&b0p_s[pb];
        unsigned int wqa[4] = {wq.x, wq.y, wq.z, wq.w};
        unsigned int bqa[4] = {bq.x, bq.y, bq.z, bq.w};
        #pragma unroll
        for (int i = 0; i < 4; ++i) {
            union { unsigned int u; h2 h; } cw, cb;
            cw.u = wqa[i]; cb.u = bqa[i];
            h2 z = {(_Float16)0.f, (_Float16)0.f};
            #pragma unroll
            for (int j = 0; j < 2; ++j) {
                h2 r = __builtin_elementwise_fma(uu[j], cw.h, cb.h);
                a1[j][ks].h[i] = __builtin_elementwise_max(r, z);
            }
        }
    }

    // layer 2: dual accumulators share weight loads; pack+exchange -> f3
    FR f3[2][7];
    #pragma unroll
    for (int nt = 0; nt < 4; ++nt) {
        f32x16 acc[2];
        #pragma unroll
        for (int r = 0; r < 16; ++r) { acc[0][r] = 0.f; acc[1][r] = 0.f; }
        #pragma unroll
        for (int ks = 0; ks < 7; ++ks) {
            f16x8 wA = *(const f16x8*)&W1s[wrow[nt] + ks * 16 + zoff];
            acc[0] = __builtin_amdgcn_mfma_f32_32x32x16_f16(wA, a1[0][ks].v, acc[0], 0, 0, 0);
            acc[1] = __builtin_amdgcn_mfma_f32_32x32x16_f16(wA, a1[1][ks].v, acc[1], 0, 0, 0);
        }
        #pragma unroll
        for (int j = 0; j < 2; ++j) {
            if (nt < 3) {
                unsigned int pk[4][2];
                #pragma unroll
                for (int qi = 0; qi < 4; ++qi) {
                    f32x2 lo = {acc[j][4 * qi + 0], acc[j][4 * qi + 1]};
                    f32x2 hi = {acc[j][4 * qi + 2], acc[j][4 * qi + 3]};
                    lo = __builtin_elementwise_max(lo, zero2);
                    hi = __builtin_elementwise_max(hi, zero2);
                    pk[qi][0] = hpk(lo[0], lo[1]);
                    pk[qi][1] = hpk(hi[0], hi[1]);
                }
                #pragma unroll
                for (int kk = 0; kk < 2; ++kk) {
                    unsigned int X0 = hfb ? pk[2 * kk][0] : pk[2 * kk + 1][0];
                    unsigned int X1 = hfb ? pk[2 * kk][1] : pk[2 * kk + 1][1];
                    unsigned int O0 = hfb ? pk[2 * kk + 1][0] : pk[2 * kk][0];
                    unsigned int O1 = hfb ? pk[2 * kk + 1][1] : pk[2 * kk][1];
                    unsigned int Y0 = (unsigned int)__shfl_xor((int)X0, 32, 64);
                    unsigned int Y1 = (unsigned int)__shfl_xor((int)X1, 32, 64);
                    f3[j][nt * 2 + kk].u32[0] = hfb ? Y0 : O0;
                    f3[j][nt * 2 + kk].u32[1] = hfb ? Y1 : O1;
                    f3[j][nt * 2 + kk].u32[2] = hfb ? O0 : Y0;
                    f3[j][nt * 2 + kk].u32[3] = hfb ? O1 : Y1;
                }
            } else {
                f32x2 lo = {acc[j][0], acc[j][1]};
                f32x2 hi = {acc[j][2], acc[j][3]};
                lo = __builtin_elementwise_max(lo, zero2);
                hi = __builtin_elementwise_max(hi, zero2);
                unsigned int p0 = hpk(lo[0], lo[1]);
                unsigned int p1 = hpk(hi[0], hi[1]);
                f3[j][6].u32[0] = hfb ? 0u : p0;
                f3[j][6].u32[1] = hfb ? 0u : p1;
                f3[j][6].u32[2] = hfb ? 0u : 0x00003C00u;   // f16 1.0 (bias slot)
                f3[j][6].u32[3] = 0u;
            }
        }
    }

    // layer 3: dual accumulators; shared W2 + w3 loads; fold w3
    f32x2 oacc2[2] = {{0.f, 0.f}, {0.f, 0.f}};
    #pragma unroll
    for (int nt2 = 0; nt2 < 4; ++nt2) {
        f32x16 acc2[2];
        #pragma unroll
        for (int r = 0; r < 16; ++r) { acc2[0][r] = 0.f; acc2[1][r] = 0.f; }
        #pragma unroll
        for (int ks = 0; ks < 7; ++ks) {
            f16x8 wA = *(const f16x8*)&W2s[wrow[nt2] + ks * 16 + zoff];
            acc2[0] = __builtin_amdgcn_mfma_f32_32x32x16_f16(wA, f3[0][ks].v, acc2[0], 0, 0, 0);
            acc2[1] = __builtin_amdgcn_mfma_f32_32x32x16_f16(wA, f3[1][ks].v, acc2[1], 0, 0, 0);
        }
        uint4 wa = *(const uint4*)&w3p_s[hf * 32 + nt2 * 8 + zoff];
        uint4 wb2 = *(const uint4*)&w3p_s[hf * 32 + nt2 * 8 + 4 + zoff];
        unsigned int w8[8] = {wa.x, wa.y, wa.z, wa.w, wb2.x, wb2.y, wb2.z, wb2.w};
        f32x2 w3v[8];
        #pragma unroll
        for (int q = 0; q < 8; ++q) {
            w3v[q][0] = __uint_as_float(w8[q] << 16);
            w3v[q][1] = __uint_as_float(w8[q] & 0xFFFF0000u);
        }
        #pragma unroll
        for (int j = 0; j < 2; ++j)
            #pragma unroll
            for (int qi = 0; qi < 4; ++qi) {
                f32x2 lo = {acc2[j][4 * qi + 0], acc2[j][4 * qi + 1]};
                f32x2 hi = {acc2[j][4 * qi + 2], acc2[j][4 * qi + 3]};
                lo = __builtin_elementwise_max(lo, zero2);
                hi = __builtin_elementwise_max(hi, zero2);
                oacc2[j] = __builtin_elementwise_fma(lo, w3v[qi * 2], oacc2[j]);
                oacc2[j] = __builtin_elementwise_fma(hi, w3v[qi * 2 + 1], oacc2[j]);
            }
    }

    #pragma unroll
    for (int j = 0; j < 2; ++j) {
        float oacc = oacc2[j][0] + oacc2[j][1];
        float o = oacc + __shfl_xor(oacc, 32, 64) + b3;
        dzout[j] = (o > 0.f) ? (o + 1.f) : expf(o);   // elu(o) + 1
    }
}

// quadrature of one net's table: z = sum_p ccw[p] * lerp(tab, x*xsc[p]),
// 4 threads/sample (point-strided), butterfly reduce over the 4-lane group.
__device__ __forceinline__ float quadz(const float* __restrict__ tab_s,
                                       const float* __restrict__ xsc_s,
                                       const float* __restrict__ ccw_s,
                                       float x, float u0, float invd, int psub)
{
    float z = 0.f;
    for (int p = psub; p < 101; p += 4) {
        float u = x * xsc_s[p];
        float tt = fminf(fmaxf((u - u0) * invd, 0.f), (float)(G - 1) - 0.001f);
        int i = (int)tt;
        float f = tt - (float)i;
        float g0 = tab_s[i];
        float g1 = tab_s[i + 1];
        z = fmaf(ccw_s[p], fmaf(f, g1 - g0, g0), z);
    }
    z += __shfl_xor(z, 1, 64);
    z += __shfl_xor(z, 2, 64);
    return z;
}

// Single kernel, manual grid barriers:
//  A: passthrough + minmax partials (all), h-MLP (blocks 0-2), CC consts (block 3)
//  B: build tables 0,1 (blocks 0-31, self-reduced range) || probe (block 48)
//     || net-2 weight staging (blocks 32-47)
//  C: build table 2 (blocks 32-47) || pre-stage tables 0,1 + consts (others)
//  D: stage remaining table(s), eval y1 + register-chained x2->y2 (all blocks)
__global__ __launch_bounds__(256, 2)
void mega_kernel(const float* __restrict__ logits,
                 const float* __restrict__ iW0, const float* __restrict__ ib0,
                 const float* __restrict__ iW1, const float* __restrict__ ib1,
                 const float* __restrict__ iW2, const float* __restrict__ ib2,
                 const float* __restrict__ iW3, const float* __restrict__ ib3,
                 const float* __restrict__ hb0,
                 const float* __restrict__ hW1, const float* __restrict__ hb1,
                 const float* __restrict__ hW2, const float* __restrict__ hb2,
                 const float* __restrict__ hW3, const float* __restrict__ hb3,
                 float* __restrict__ ws, float* __restrict__ out, int n)
{
    __shared__ MegaSh sh;
    __shared__ float xsc_s[104], ccw_s[104];
    __shared__ float rmin_s[4], rmax_s[4];
    __shared__ float xmM_s[2];
    __shared__ float rng_s[2];      // this block's build {u0, dlt}

    int* bar = (int*)(ws + WS_BAR);
    const int tid = threadIdx.x;
    const int b = blockIdx.x;
    const int lane = tid & 63;
    const int wv = tid >> 6;
    const int hf = lane >> 5;
    const bool hfb = (hf != 0);
    const int l31 = lane & 31;
    const int spb = (n + NBLK - 1) / NBLK;      // 64 at n=16384
    const int ibeg = b * spb;
    const int iend = (ibeg + spb < n) ? (ibeg + spb) : n;

    // ---------------- phase A ----------------
    {
        float lmin = 1e30f, lmax = -1e30f;
        for (int i = ibeg + tid; i < iend; i += 256) {
            float v = logits[i];
            out[2 * n + i] = v;
            lmin = fminf(lmin, v);
            lmax = fmaxf(lmax, v);
        }
        #pragma unroll
        for (int off = 1; off < 64; off <<= 1) {
            lmin = fminf(lmin, __shfl_xor(lmin, off, 64));
            lmax = fmaxf(lmax, __shfl_xor(lmax, off, 64));
        }
        if (lane == 0) { rmin_s[wv] = lmin; rmax_s[wv] = lmax; }
    }
    __syncthreads();
    if (tid == 0) {
        ws[WS_P01 + 2 * b]     = fminf(fminf(rmin_s[0], rmin_s[1]), fminf(rmin_s[2], rmin_s[3]));
        ws[WS_P01 + 2 * b + 1] = fmaxf(fmaxf(rmax_s[0], rmax_s[1]), fmaxf(rmax_s[2], rmax_s[3]));
    }

    if (b == 3) {
        // CC quadrature consts (verified 51-term double loop)
        if (tid < 128) {
            double ccw = 0.0, xs = 0.0;
            if (tid <= 100) {
                double s = (double)tid;
                for (int j = 0; j <= 100; j += 2) {
                    double wj = (j == 0) ? 1.0 : 2.0 / (1.0 - (double)j * (double)j);
                    double lam;
                    if (tid == 0) lam = 0.5;
                    else {
                        lam = cos((double)j * s * M_PI / 100.0);
                        if (tid == 100) lam *= 0.5;
                    }
                    ccw += lam * 0.02 * wj;
                }
                xs = (cos(s * M_PI / 100.0) + 1.0) * 0.5;
            }
            if (tid <= 100) {
                ws[WS_CCW + tid] = (float)ccw;
                ws[WS_XSC + tid] = (float)xs;
            }
        }
    } else if (b < 3) {
        const int k = b;                       // one net per block
        if (tid < 128) sh.prep.bufA[tid] = (tid < DH) ? fmaxf(hb0[k * DH + tid], 0.f) : 0.f;
        __syncthreads();
        for (int i = tid; i < DH * DH; i += 256) {
            int r = i / DH, c = i - r * DH;
            sh.prep.hw[r * 101 + c] = hW1[k * DH * DH + i];
        }
        __syncthreads();
        if (tid < DH) {
            float acc = hb1[k * DH + tid];
            for (int i = 0; i < DH; ++i) acc = fmaf(sh.prep.hw[tid * 101 + i], sh.prep.bufA[i], acc);
            sh.prep.bufB[tid] = fmaxf(acc, 0.f);
        }
        __syncthreads();
        for (int i = tid; i < DH * DH; i += 256) {
            int r = i / DH, c = i - r * DH;
            sh.prep.hw[r * 101 + c] = hW2[k * DH * DH + i];
        }
        __syncthreads();
        if (tid < DH) {
            float acc = hb2[k * DH + tid];
            for (int i = 0; i < DH; ++i) acc = fmaf(sh.prep.hw[tid * 101 + i], sh.prep.bufB[i], acc);
            sh.prep.bufA[tid] = fmaxf(acc, 0.f);
        }
        __syncthreads();
        if (tid < 2) {
            float acc = hb3[k * 2 + tid];
            const float* w = hW3 + (size_t)(k * 2 + tid) * DH;
            for (int i = 0; i < DH; ++i) acc = fmaf(w[i], sh.prep.bufA[i], acc);
            if (tid == 0) ws[WS_OH0 + k] = acc;
            else          ws[WS_EOH1 + k] = expf(acc);
        }
    }
    gridbar(bar, 0);

    // ---------------- phase B ----------------
    unsigned int zoff = 0;
    asm volatile("" : "+v"(zoff));   // opaque zero (keeps LDS reads un-cached)

    const bool role_build01 = (b < 32);
    const bool role_stage2  = (b >= 32 && b < 48);
    const bool role_probe   = (b == 48);

    int wrow[4];
    #pragma unroll
    for (int nt = 0; nt < 4; ++nt) {
        int r = nt * 32 + l31;
        wrow[nt] = ((r > DH - 1) ? (DH - 1) : r) * WSTR + hf * 8;
    }

    if (b < 49) {
        const int kk = role_probe ? 0 : (b >> 4);
        if (tid < 64) {
            int s0 = 2 * tid, s1 = 2 * tid + 1;
            float w0a = (s0 < DH) ? iW0[(kk * DH + s0) * 3] : 0.f;   // h==0: feature 0 only
            float w0b = (s1 < DH) ? iW0[(kk * DH + s1) * 3] : 0.f;
            float b0a = (s0 < DH) ? ib0[kk * DH + s0] : ((s0 == DH) ? 1.f : 0.f);
            float b0b = (s1 < DH) ? ib0[kk * DH + s1] : 0.f;
            sh.mlp.w0p[tid] = hpk(w0a, w0b);
            sh.mlp.b0p[tid] = hpk(b0a, b0b);

            int hf_i = tid >> 5, rem = tid & 31;
            int nt2 = rem >> 3, qq = (rem >> 1) & 3, pr = rem & 1;
            int n2e = 32 * nt2 + 8 * qq + 2 * pr + 4 * hf_i;
            float we = (n2e < DH) ? iW3[kk * DH + n2e] : 0.f;
            float wo = (n2e + 1 < DH) ? iW3[kk * DH + n2e + 1] : 0.f;
            sh.mlp.w3p[tid] = ((unsigned int)f2bf(wo) << 16) | (unsigned int)f2bf(we);

            // every staging/probing block reduces the logits range itself
            float pm = 1e30f, pM = -1e30f;
            for (int i = tid; i < NBLK; i += 64) {
                pm = fminf(pm, ws[WS_P01 + 2 * i]);
                pM = fmaxf(pM, ws[WS_P01 + 2 * i + 1]);
            }
            #pragma unroll
            for (int off = 1; off < 64; off <<= 1) {
                pm = fminf(pm, __shfl_xor(pm, off, 64));
                pM = fmaxf(pM, __shfl_xor(pM, off, 64));
            }
            if (tid == 0) {
                float um = fminf(pm, 0.f), uM = fmaxf(pM, 0.f);
                float span = fmaxf(uM - um, 1e-5f);
                float d = span * (1.f / (float)(G - 1));
                float iv = (float)(G - 1) / span;
                rng_s[0] = um; rng_s[1] = d;
                xmM_s[0] = pm; xmM_s[1] = pM;
                if (role_probe) {
                    ws[WS_RNG + 0] = um; ws[WS_RNG + 1] = d; ws[WS_RNG + 2] = iv;   // net 0
                    ws[WS_RNG + 4] = um; ws[WS_RNG + 5] = d; ws[WS_RNG + 6] = iv;   // net 1
                }
            }
        }
        const float* W1g = iW1 + (size_t)kk * DH * DH;
        const float* W2g = iW2 + (size_t)kk * DH * DH;
        for (int i = tid; i < DH * WSTR; i += 256) {
            int r = i / WSTR, c = i - r * WSTR;
            float v1, v2;
            if (c < DH)       { v1 = W1g[r * DH + c]; v2 = W2g[r * DH + c]; }
            else if (c == DH) { v1 = ib1[kk * DH + r]; v2 = ib2[kk * DH + r]; }
            else              { v1 = 0.f; v2 = 0.f; }
            sh.mlp.W1[r * WSTR + c] = (_Float16)v1;
            sh.mlp.W2[r * WSTR + c] = (_Float16)v2;
        }
        __syncthreads();   // weights + range published block-wide

        if (role_build01) {
            const int k = b >> 4;
            const float u0 = rng_s[0], dlt = rng_s[1];
            const float b3 = ib3[k];
            float* __restrict__ tab = ws + WS_TAB + k * G;
            int mr[2];
            h2 uu[2];
            #pragma unroll
            for (int j = 0; j < 2; ++j) {
                mr[j] = (b & 15) * 256 + j * 128 + wv * 32 + l31;
                float u = fmaf((float)mr[j], dlt, u0);
                uu[j] = hpk2(u, u);
            }
            float dz[2];
            mlp2(sh.mlp.W1, sh.mlp.W2, sh.mlp.w0p, sh.mlp.b0p, sh.mlp.w3p,
                 uu, wrow, hf, hfb, b3, zoff, dz);
            #pragma unroll
            for (int j = 0; j < 2; ++j) if (!hfb) tab[mr[j]] = dz[j];
        } else if (role_probe) {
            const float xm = xmM_s[0], xM = xmM_s[1];
            const float b3 = ib3[0];
            // rows: r = e*101 + p (e in {0,1}: xmin/xmax endpoint, p quad pt)
            int rr[2];
            h2 uu[2];
            #pragma unroll
            for (int j = 0; j < 2; ++j) {
                rr[j] = j * 128 + wv * 32 + l31;
                int r = rr[j];
                float xe = (r < 101) ? xm : xM;
                int p = (r < 101) ? r : (r - 101);
                if (p > 100) p = 0;
                float u = (r < 202) ? xe * ws[WS_XSC + p] : 0.f;
                uu[j] = hpk2(u, u);
            }
            float dz[2];
            mlp2(sh.mlp.W1, sh.mlp.W2, sh.mlp.w0p, sh.mlp.b0p, sh.mlp.w3p,
                 uu, wrow, hf, hfb, b3, zoff, dz);
            #pragma unroll
            for (int j = 0; j < 2; ++j) if (!hfb) sh.mlp.g[rr[j]] = dz[j];
            __syncthreads();

            // quadrature at both endpoints -> x2 range -> net-2 table consts
            if (tid < 64) {
                float s0a = 0.f, s1a = 0.f;
                for (int p = tid; p < 101; p += 64) {
                    float c = ws[WS_CCW + p];
                    s0a = fmaf(c, sh.mlp.g[p], s0a);
                    s1a = fmaf(c, sh.mlp.g[101 + p], s1a);
                }
                #pragma unroll
                for (int off = 1; off < 64; off <<= 1) {
                    s0a += __shfl_xor(s0a, off, 64);
                    s1a += __shfl_xor(s1a, off, 64);
                }
                if (tid == 0) {
                    float z0 = 0.5f * xm * s0a;
                    float z1 = 0.5f * xM * s1a;
                    float o0 = ws[WS_OH0 + 0], e1 = ws[WS_EOH1 + 0];
                    float a = fmaf(e1, z0, o0);
                    float bb = fmaf(e1, z1, o0);
                    float x2m = fminf(a, bb), x2M = fmaxf(a, bb);
                    float sp = fmaxf(x2M - x2m, 1e-6f);
                    x2m -= 0.02f * sp;                 // safety margin: quadrature
                    x2M += 0.02f * sp;                 // wiggle + table-lerp error
                    float um = fminf(x2m, 0.f), uM = fmaxf(x2M, 0.f);
                    float span = fmaxf(uM - um, 1e-5f);
                    ws[WS_RNG + 8]  = um;
                    ws[WS_RNG + 9]  = span * (1.f / (float)(G - 1));
                    ws[WS_RNG + 10] = (float)(G - 1) / span;
                }
            }
        }
    }
    gridbar(bar, 1);

    // ---------------- phase C: build table 2 || pre-stage tables 0,1 ----------------
    if (role_stage2) {
        const float u0 = ws[WS_RNG + 8];
        const float dlt = ws[WS_RNG + 9];
        const float b3 = ib3[2];
        float* __restrict__ tab = ws + WS_TAB + 2 * G;
        int mr[2];
        h2 uu[2];
        #pragma unroll
        for (int j = 0; j < 2; ++j) {
            mr[j] = (b & 15) * 256 + j * 128 + wv * 32 + l31;
            float u = fmaf((float)mr[j], dlt, u0);
            uu[j] = hpk2(u, u);
        }
        float dz[2];
        mlp2(sh.mlp.W1, sh.mlp.W2, sh.mlp.w0p, sh.mlp.b0p, sh.mlp.w3p,
             uu, wrow, hf, hfb, b3, zoff, dz);
        #pragma unroll
        for (int j = 0; j < 2; ++j) if (!hfb) tab[mr[j]] = dz[j];
    } else {
        const float* tg = ws + WS_TAB;
        for (int i = tid * 4; i < 2 * G; i += 1024)
            *(float4*)&sh.ev.tab[i] = *(const float4*)&tg[i];
        if (tid < 101) {
            xsc_s[tid] = ws[WS_XSC + tid];
            ccw_s[tid] = ws[WS_CCW + tid];
        }
    }
    gridbar(bar, 2);

    // ---------------- phase D: eval ----------------
    {
        const float* tg = ws + WS_TAB;
        if (role_stage2) {
            for (int i = tid * 4; i < 3 * G; i += 1024)
                *(float4*)&sh.ev.tab[i] = *(const float4*)&tg[i];
            if (tid < 101) {
                xsc_s[tid] = ws[WS_XSC + tid];
                ccw_s[tid] = ws[WS_CCW + tid];
            }
        } else {
            for (int i = 2 * G + tid * 4; i < 3 * G; i += 1024)
                *(float4*)&sh.ev.tab[i] = *(const float4*)&tg[i];
        }
        __syncthreads();

        const float u00 = ws[WS_RNG + 0], iv0v = ws[WS_RNG + 2];
        const float u01 = ws[WS_RNG + 4], iv1v = ws[WS_RNG + 6];
        const float u02 = ws[WS_RNG + 8], iv2v = ws[WS_RNG + 10];
        const float o00 = ws[WS_OH0 + 0], e10 = ws[WS_EOH1 + 0];
        const float o01 = ws[WS_OH0 + 1], e11 = ws[WS_EOH1 + 1];
        const float o02 = ws[WS_OH0 + 2], e12 = ws[WS_EOH1 + 2];
        const int psub = tid & 3;

        for (int nn0 = ibeg; nn0 < iend; nn0 += 64) {
            int nn = nn0 + (tid >> 2);
            bool valid = (nn < iend);
            float x = valid ? logits[nn] : 0.f;

            float z1 = quadz(sh.ev.tab + G, xsc_s, ccw_s, x, u01, iv1v, psub);
            float y1v = fmaf(e11, 0.5f * x * z1, o01);

            float z0 = quadz(sh.ev.tab, xsc_s, ccw_s, x, u00, iv0v, psub);
            float x2 = fmaf(e10, 0.5f * x * z0, o00);

            float z2 = quadz(sh.ev.tab + 2 * G, xsc_s, ccw_s, x2, u02, iv2v, psub);
            float y2v = fmaf(e12, 0.5f * x2 * z2, o02);

            if (valid && psub == 0) {
                out[nn] = y1v;
                out[n + nn] = y2v;
            }
        }
    }
}

extern "C" void kernel_launch(void* const* d_in, const int* in_sizes, int n_in,
                              void* d_out, int out_size, void* d_ws, size_t ws_size,
                              hipStream_t stream)
{
    const float* logits = (const float*)d_in[0];
    const float* iW0 = (const float*)d_in[2];
    const float* ib0 = (const float*)d_in[3];
    const float* iW1 = (const float*)d_in[4];
    const float* ib1 = (const float*)d_in[5];
    const float* iW2 = (const float*)d_in[6];
    const float* ib2 = (const float*)d_in[7];
    const float* iW3 = (const float*)d_in[8];
    const float* ib3 = (const float*)d_in[9];
    const float* hb0 = (const float*)d_in[11];
    const float* hW1 = (const float*)d_in[12];
    const float* hb1 = (const float*)d_in[13];
    const float* hW2 = (const float*)d_in[14];
    const float* hb2 = (const float*)d_in[15];
    const float* hW3 = (const float*)d_in[16];
    const float* hb3 = (const float*)d_in[17];
    float* out = (float*)d_out;
    float* ws = (float*)d_ws;
    int n = in_sizes[0];

    // zero the one-shot grid-barrier counters (captured per-iteration)
    hipMemsetAsync((void*)(ws + WS_BAR), 0, 4 * sizeof(int), stream);

    hipLaunchKernelGGL(mega_kernel, dim3(NBLK), dim3(256), 0, stream,
                       logits, iW0, ib0, iW1, ib1, iW2, ib2, iW3, ib3,
                       hb0, hW1, hb1, hW2, hb2, hW3, hb3, ws, out, n);
}

// Round 4
// 178.140 us; speedup vs baseline: 1.8258x; 1.8258x over previous
//
#include <hip/hip_runtime.h>
#include <hip/hip_bf16.h>
#include <hip/hip_fp16.h>
#include <math.h>

typedef _Float16 f16x8 __attribute__((ext_vector_type(8)));
typedef _Float16 h2 __attribute__((ext_vector_type(2)));
typedef __fp16 h2amd __attribute__((ext_vector_type(2)));   // builtin return type
typedef float f32x16 __attribute__((ext_vector_type(16)));
typedef float f32x2 __attribute__((ext_vector_type(2)));

#define DH 100      // hidden dim
#define G  4096     // table size per net
#define WSTR 120    // LDS row stride in f16 elems
#define NBLK 256    // grid size; capacity argument guarantees co-residency:
                    // __launch_bounds__(256,2) => VGPR<=256, LDS ~51KB < 80KB
                    // => every CU hosts >=2 blocks => capacity 512 >= 256.

// ws float offsets
#define WS_CCW   0      // [0,101)
#define WS_XSC   128    // [128,229)
#define WS_OH0   256    // 3
#define WS_EOH1  260    // 3
#define WS_P01   264    // NBLK min/max pairs (logits)  [264,776)
#define WS_RNG   800    // 3 nets x {u0, dlt, inv, pad} [800,812)
#define WS_BAR   960    // 4 ints: one-shot grid barrier counters
#define WS_TAB   17408  // 3*G table floats

__device__ __forceinline__ unsigned short f2bf(float f) {
    unsigned int u = __float_as_uint(f);
    unsigned int r = (u + 0x7FFFu + ((u >> 16) & 1u)) >> 16;  // RNE
    return (unsigned short)r;
}
__device__ __forceinline__ unsigned int hpk(float a, float b) {
    union { h2amd h; unsigned int u; } c;
    c.h = __builtin_amdgcn_cvt_pkrtz(a, b);
    return c.u;
}
__device__ __forceinline__ h2 hpk2(float a, float b) {
    union { h2amd ha; h2 h; } c;
    c.ha = __builtin_amdgcn_cvt_pkrtz(a, b);
    return c.h;
}

// one-shot grid barrier. R3 post-mortem: ACQUIRE-polling emitted a cache
// invalidate PER POLL (per-XCD L2 non-coherent => agent acquire = buffer_inv),
// 256 pollers x invalidate storm = ~85us/barrier. Fix: RELAXED add + RELAXED
// poll (agent-scope atomics bypass the non-coherent caches via sc-bits, so
// remote updates are observed without maintenance ops); exactly one release
// fence before arrival and one acquire fence after exit.
__device__ __forceinline__ void gridbar(int* bar, int idx) {
    __syncthreads();
    if (threadIdx.x == 0) {
        __threadfence();   // release: make prior global writes visible agent-wide
        __hip_atomic_fetch_add(&bar[idx], 1, __ATOMIC_RELAXED, __HIP_MEMORY_SCOPE_AGENT);
        while (__hip_atomic_load(&bar[idx], __ATOMIC_RELAXED, __HIP_MEMORY_SCOPE_AGENT) < NBLK)
            __builtin_amdgcn_s_sleep(2);
        __threadfence();   // acquire: drop stale cached lines (once)
    }
    __syncthreads();
}

union FR { f16x8 v; h2 h[4]; unsigned int u32[4]; };

// phase-overlaid LDS (max member ~49.8 KB)
union MegaSh {
    struct { float hw[DH * 101]; float bufA[128]; float bufB[128]; } prep;
    struct {
        __align__(16) _Float16 W1[DH * WSTR];
        __align__(16) _Float16 W2[DH * WSTR];
        unsigned int w0p[64], b0p[64], w3p[64];
        float g[256];
    } mlp;
    struct { __align__(16) float tab[3 * G]; } ev;
};

// R3-R11-verified transposed MFMA dataflow (lane^32 exchange, laundered LDS
// reads): evaluates g(u)=elu(MLP(u))+1 for the two 128-row groups. dzout[j]
// is valid on !hfb lanes.
__device__ __forceinline__ void mlp2(const _Float16* __restrict__ W1s,
                                     const _Float16* __restrict__ W2s,
                                     const unsigned int* __restrict__ w0p_s,
                                     const unsigned int* __restrict__ b0p_s,
                                     const unsigned int* __restrict__ w3p_s,
                                     const h2* uu, const int* wrow,
                                     const int hf, const bool hfb,
                                     const float b3, unsigned int zoff,
                                     float* dzout)
{
    const f32x2 zero2 = {0.f, 0.f};

    // layer 1: B-frags for both row groups, shared w0/b0 loads
    FR a1[2][7];
    #pragma unroll
    for (int ks = 0; ks < 7; ++ks) {
        int pb = ks * 8 + hf * 4 + zoff;
        uint4 wq = *(const uint4*)&w0p_s[pb];
        uint4 bq = *(const uint4*)&b0p_s[pb];
        unsigned int wqa[4] = {wq.x, wq.y, wq.z, wq.w};
        unsigned int bqa[4] = {bq.x, bq.y, bq.z, bq.w};
        #pragma unroll
        for (int i = 0; i < 4; ++i) {
            union { unsigned int u; h2 h; } cw, cb;
            cw.u = wqa[i]; cb.u = bqa[i];
            h2 z = {(_Float16)0.f, (_Float16)0.f};
            #pragma unroll
            for (int j = 0; j < 2; ++j) {
                h2 r = __builtin_elementwise_fma(uu[j], cw.h, cb.h);
                a1[j][ks].h[i] = __builtin_elementwise_max(r, z);
            }
        }
    }

    // layer 2: dual accumulators share weight loads; pack+exchange -> f3
    FR f3[2][7];
    #pragma unroll
    for (int nt = 0; nt < 4; ++nt) {
        f32x16 acc[2];
        #pragma unroll
        for (int r = 0; r < 16; ++r) { acc[0][r] = 0.f; acc[1][r] = 0.f; }
        #pragma unroll
        for (int ks = 0; ks < 7; ++ks) {
            f16x8 wA = *(const f16x8*)&W1s[wrow[nt] + ks * 16 + zoff];
            acc[0] = __builtin_amdgcn_mfma_f32_32x32x16_f16(wA, a1[0][ks].v, acc[0], 0, 0, 0);
            acc[1] = __builtin_amdgcn_mfma_f32_32x32x16_f16(wA, a1[1][ks].v, acc[1], 0, 0, 0);
        }
        #pragma unroll
        for (int j = 0; j < 2; ++j) {
            if (nt < 3) {
                unsigned int pk[4][2];
                #pragma unroll
                for (int qi = 0; qi < 4; ++qi) {
                    f32x2 lo = {acc[j][4 * qi + 0], acc[j][4 * qi + 1]};
                    f32x2 hi = {acc[j][4 * qi + 2], acc[j][4 * qi + 3]};
                    lo = __builtin_elementwise_max(lo, zero2);
                    hi = __builtin_elementwise_max(hi, zero2);
                    pk[qi][0] = hpk(lo[0], lo[1]);
                    pk[qi][1] = hpk(hi[0], hi[1]);
                }
                #pragma unroll
                for (int kk = 0; kk < 2; ++kk) {
                    unsigned int X0 = hfb ? pk[2 * kk][0] : pk[2 * kk + 1][0];
                    unsigned int X1 = hfb ? pk[2 * kk][1] : pk[2 * kk + 1][1];
                    unsigned int O0 = hfb ? pk[2 * kk + 1][0] : pk[2 * kk][0];
                    unsigned int O1 = hfb ? pk[2 * kk + 1][1] : pk[2 * kk][1];
                    unsigned int Y0 = (unsigned int)__shfl_xor((int)X0, 32, 64);
                    unsigned int Y1 = (unsigned int)__shfl_xor((int)X1, 32, 64);
                    f3[j][nt * 2 + kk].u32[0] = hfb ? Y0 : O0;
                    f3[j][nt * 2 + kk].u32[1] = hfb ? Y1 : O1;
                    f3[j][nt * 2 + kk].u32[2] = hfb ? O0 : Y0;
                    f3[j][nt * 2 + kk].u32[3] = hfb ? O1 : Y1;
                }
            } else {
                f32x2 lo = {acc[j][0], acc[j][1]};
                f32x2 hi = {acc[j][2], acc[j][3]};
                lo = __builtin_elementwise_max(lo, zero2);
                hi = __builtin_elementwise_max(hi, zero2);
                unsigned int p0 = hpk(lo[0], lo[1]);
                unsigned int p1 = hpk(hi[0], hi[1]);
                f3[j][6].u32[0] = hfb ? 0u : p0;
                f3[j][6].u32[1] = hfb ? 0u : p1;
                f3[j][6].u32[2] = hfb ? 0u : 0x00003C00u;   // f16 1.0 (bias slot)
                f3[j][6].u32[3] = 0u;
            }
        }
    }

    // layer 3: dual accumulators; shared W2 + w3 loads; fold w3
    f32x2 oacc2[2] = {{0.f, 0.f}, {0.f, 0.f}};
    #pragma unroll
    for (int nt2 = 0; nt2 < 4; ++nt2) {
        f32x16 acc2[2];
        #pragma unroll
        for (int r = 0; r < 16; ++r) { acc2[0][r] = 0.f; acc2[1][r] = 0.f; }
        #pragma unroll
        for (int ks = 0; ks < 7; ++ks) {
            f16x8 wA = *(const f16x8*)&W2s[wrow[nt2] + ks * 16 + zoff];
            acc2[0] = __builtin_amdgcn_mfma_f32_32x32x16_f16(wA, f3[0][ks].v, acc2[0], 0, 0, 0);
            acc2[1] = __builtin_amdgcn_mfma_f32_32x32x16_f16(wA, f3[1][ks].v, acc2[1], 0, 0, 0);
        }
        uint4 wa = *(const uint4*)&w3p_s[hf * 32 + nt2 * 8 + zoff];
        uint4 wb2 = *(const uint4*)&w3p_s[hf * 32 + nt2 * 8 + 4 + zoff];
        unsigned int w8[8] = {wa.x, wa.y, wa.z, wa.w, wb2.x, wb2.y, wb2.z, wb2.w};
        f32x2 w3v[8];
        #pragma unroll
        for (int q = 0; q < 8; ++q) {
            w3v[q][0] = __uint_as_float(w8[q] << 16);
            w3v[q][1] = __uint_as_float(w8[q] & 0xFFFF0000u);
        }
        #pragma unroll
        for (int j = 0; j < 2; ++j)
            #pragma unroll
            for (int qi = 0; qi < 4; ++qi) {
                f32x2 lo = {acc2[j][4 * qi + 0], acc2[j][4 * qi + 1]};
                f32x2 hi = {acc2[j][4 * qi + 2], acc2[j][4 * qi + 3]};
                lo = __builtin_elementwise_max(lo, zero2);
                hi = __builtin_elementwise_max(hi, zero2);
                oacc2[j] = __builtin_elementwise_fma(lo, w3v[qi * 2], oacc2[j]);
                oacc2[j] = __builtin_elementwise_fma(hi, w3v[qi * 2 + 1], oacc2[j]);
            }
    }

    #pragma unroll
    for (int j = 0; j < 2; ++j) {
        float oacc = oacc2[j][0] + oacc2[j][1];
        float o = oacc + __shfl_xor(oacc, 32, 64) + b3;
        dzout[j] = (o > 0.f) ? (o + 1.f) : expf(o);   // elu(o) + 1
    }
}

// quadrature of one net's table: z = sum_p ccw[p] * lerp(tab, x*xsc[p]),
// 4 threads/sample (point-strided), butterfly reduce over the 4-lane group.
__device__ __forceinline__ float quadz(const float* __restrict__ tab_s,
                                       const float* __restrict__ xsc_s,
                                       const float* __restrict__ ccw_s,
                                       float x, float u0, float invd, int psub)
{
    float z = 0.f;
    for (int p = psub; p < 101; p += 4) {
        float u = x * xsc_s[p];
        float tt = fminf(fmaxf((u - u0) * invd, 0.f), (float)(G - 1) - 0.001f);
        int i = (int)tt;
        float f = tt - (float)i;
        float g0 = tab_s[i];
        float g1 = tab_s[i + 1];
        z = fmaf(ccw_s[p], fmaf(f, g1 - g0, g0), z);
    }
    z += __shfl_xor(z, 1, 64);
    z += __shfl_xor(z, 2, 64);
    return z;
}

// Single kernel, manual grid barriers:
//  A: passthrough + minmax partials (all), h-MLP (blocks 0-2), CC consts (block 3)
//  B: build tables 0,1 (blocks 0-31, self-reduced range) || probe (block 48)
//     || net-2 weight staging (blocks 32-47)
//  C: build table 2 (blocks 32-47) || pre-stage tables 0,1 + consts (others)
//  D: stage remaining table(s), eval y1 + register-chained x2->y2 (all blocks)
__global__ __launch_bounds__(256, 2)
void mega_kernel(const float* __restrict__ logits,
                 const float* __restrict__ iW0, const float* __restrict__ ib0,
                 const float* __restrict__ iW1, const float* __restrict__ ib1,
                 const float* __restrict__ iW2, const float* __restrict__ ib2,
                 const float* __restrict__ iW3, const float* __restrict__ ib3,
                 const float* __restrict__ hb0,
                 const float* __restrict__ hW1, const float* __restrict__ hb1,
                 const float* __restrict__ hW2, const float* __restrict__ hb2,
                 const float* __restrict__ hW3, const float* __restrict__ hb3,
                 float* __restrict__ ws, float* __restrict__ out, int n)
{
    __shared__ MegaSh sh;
    __shared__ float xsc_s[104], ccw_s[104];
    __shared__ float rmin_s[4], rmax_s[4];
    __shared__ float xmM_s[2];
    __shared__ float rng_s[2];      // this block's build {u0, dlt}

    int* bar = (int*)(ws + WS_BAR);
    const int tid = threadIdx.x;
    const int b = blockIdx.x;
    const int lane = tid & 63;
    const int wv = tid >> 6;
    const int hf = lane >> 5;
    const bool hfb = (hf != 0);
    const int l31 = lane & 31;
    const int spb = (n + NBLK - 1) / NBLK;      // 64 at n=16384
    const int ibeg = b * spb;
    const int iend = (ibeg + spb < n) ? (ibeg + spb) : n;

    // ---------------- phase A ----------------
    {
        float lmin = 1e30f, lmax = -1e30f;
        for (int i = ibeg + tid; i < iend; i += 256) {
            float v = logits[i];
            out[2 * n + i] = v;
            lmin = fminf(lmin, v);
            lmax = fmaxf(lmax, v);
        }
        #pragma unroll
        for (int off = 1; off < 64; off <<= 1) {
            lmin = fminf(lmin, __shfl_xor(lmin, off, 64));
            lmax = fmaxf(lmax, __shfl_xor(lmax, off, 64));
        }
        if (lane == 0) { rmin_s[wv] = lmin; rmax_s[wv] = lmax; }
    }
    __syncthreads();
    if (tid == 0) {
        ws[WS_P01 + 2 * b]     = fminf(fminf(rmin_s[0], rmin_s[1]), fminf(rmin_s[2], rmin_s[3]));
        ws[WS_P01 + 2 * b + 1] = fmaxf(fmaxf(rmax_s[0], rmax_s[1]), fmaxf(rmax_s[2], rmax_s[3]));
    }

    if (b == 3) {
        // CC quadrature consts (verified 51-term double loop)
        if (tid < 128) {
            double ccw = 0.0, xs = 0.0;
            if (tid <= 100) {
                double s = (double)tid;
                for (int j = 0; j <= 100; j += 2) {
                    double wj = (j == 0) ? 1.0 : 2.0 / (1.0 - (double)j * (double)j);
                    double lam;
                    if (tid == 0) lam = 0.5;
                    else {
                        lam = cos((double)j * s * M_PI / 100.0);
                        if (tid == 100) lam *= 0.5;
                    }
                    ccw += lam * 0.02 * wj;
                }
                xs = (cos(s * M_PI / 100.0) + 1.0) * 0.5;
            }
            if (tid <= 100) {
                ws[WS_CCW + tid] = (float)ccw;
                ws[WS_XSC + tid] = (float)xs;
            }
        }
    } else if (b < 3) {
        const int k = b;                       // one net per block
        if (tid < 128) sh.prep.bufA[tid] = (tid < DH) ? fmaxf(hb0[k * DH + tid], 0.f) : 0.f;
        __syncthreads();
        for (int i = tid; i < DH * DH; i += 256) {
            int r = i / DH, c = i - r * DH;
            sh.prep.hw[r * 101 + c] = hW1[k * DH * DH + i];
        }
        __syncthreads();
        if (tid < DH) {
            float acc = hb1[k * DH + tid];
            for (int i = 0; i < DH; ++i) acc = fmaf(sh.prep.hw[tid * 101 + i], sh.prep.bufA[i], acc);
            sh.prep.bufB[tid] = fmaxf(acc, 0.f);
        }
        __syncthreads();
        for (int i = tid; i < DH * DH; i += 256) {
            int r = i / DH, c = i - r * DH;
            sh.prep.hw[r * 101 + c] = hW2[k * DH * DH + i];
        }
        __syncthreads();
        if (tid < DH) {
            float acc = hb2[k * DH + tid];
            for (int i = 0; i < DH; ++i) acc = fmaf(sh.prep.hw[tid * 101 + i], sh.prep.bufB[i], acc);
            sh.prep.bufA[tid] = fmaxf(acc, 0.f);
        }
        __syncthreads();
        if (tid < 2) {
            float acc = hb3[k * 2 + tid];
            const float* w = hW3 + (size_t)(k * 2 + tid) * DH;
            for (int i = 0; i < DH; ++i) acc = fmaf(w[i], sh.prep.bufA[i], acc);
            if (tid == 0) ws[WS_OH0 + k] = acc;
            else          ws[WS_EOH1 + k] = expf(acc);
        }
    }
    gridbar(bar, 0);

    // ---------------- phase B ----------------
    unsigned int zoff = 0;
    asm volatile("" : "+v"(zoff));   // opaque zero (keeps LDS reads un-cached)

    const bool role_build01 = (b < 32);
    const bool role_stage2  = (b >= 32 && b < 48);
    const bool role_probe   = (b == 48);

    int wrow[4];
    #pragma unroll
    for (int nt = 0; nt < 4; ++nt) {
        int r = nt * 32 + l31;
        wrow[nt] = ((r > DH - 1) ? (DH - 1) : r) * WSTR + hf * 8;
    }

    if (b < 49) {
        const int kk = role_probe ? 0 : (b >> 4);
        if (tid < 64) {
            int s0 = 2 * tid, s1 = 2 * tid + 1;
            float w0a = (s0 < DH) ? iW0[(kk * DH + s0) * 3] : 0.f;   // h==0: feature 0 only
            float w0b = (s1 < DH) ? iW0[(kk * DH + s1) * 3] : 0.f;
            float b0a = (s0 < DH) ? ib0[kk * DH + s0] : ((s0 == DH) ? 1.f : 0.f);
            float b0b = (s1 < DH) ? ib0[kk * DH + s1] : 0.f;
            sh.mlp.w0p[tid] = hpk(w0a, w0b);
            sh.mlp.b0p[tid] = hpk(b0a, b0b);

            int hf_i = tid >> 5, rem = tid & 31;
            int nt2 = rem >> 3, qq = (rem >> 1) & 3, pr = rem & 1;
            int n2e = 32 * nt2 + 8 * qq + 2 * pr + 4 * hf_i;
            float we = (n2e < DH) ? iW3[kk * DH + n2e] : 0.f;
            float wo = (n2e + 1 < DH) ? iW3[kk * DH + n2e + 1] : 0.f;
            sh.mlp.w3p[tid] = ((unsigned int)f2bf(wo) << 16) | (unsigned int)f2bf(we);

            // every staging/probing block reduces the logits range itself
            float pm = 1e30f, pM = -1e30f;
            for (int i = tid; i < NBLK; i += 64) {
                pm = fminf(pm, ws[WS_P01 + 2 * i]);
                pM = fmaxf(pM, ws[WS_P01 + 2 * i + 1]);
            }
            #pragma unroll
            for (int off = 1; off < 64; off <<= 1) {
                pm = fminf(pm, __shfl_xor(pm, off, 64));
                pM = fmaxf(pM, __shfl_xor(pM, off, 64));
            }
            if (tid == 0) {
                float um = fminf(pm, 0.f), uM = fmaxf(pM, 0.f);
                float span = fmaxf(uM - um, 1e-5f);
                float d = span * (1.f / (float)(G - 1));
                float iv = (float)(G - 1) / span;
                rng_s[0] = um; rng_s[1] = d;
                xmM_s[0] = pm; xmM_s[1] = pM;
                if (role_probe) {
                    ws[WS_RNG + 0] = um; ws[WS_RNG + 1] = d; ws[WS_RNG + 2] = iv;   // net 0
                    ws[WS_RNG + 4] = um; ws[WS_RNG + 5] = d; ws[WS_RNG + 6] = iv;   // net 1
                }
            }
        }
        const float* W1g = iW1 + (size_t)kk * DH * DH;
        const float* W2g = iW2 + (size_t)kk * DH * DH;
        for (int i = tid; i < DH * WSTR; i += 256) {
            int r = i / WSTR, c = i - r * WSTR;
            float v1, v2;
            if (c < DH)       { v1 = W1g[r * DH + c]; v2 = W2g[r * DH + c]; }
            else if (c == DH) { v1 = ib1[kk * DH + r]; v2 = ib2[kk * DH + r]; }
            else              { v1 = 0.f; v2 = 0.f; }
            sh.mlp.W1[r * WSTR + c] = (_Float16)v1;
            sh.mlp.W2[r * WSTR + c] = (_Float16)v2;
        }
        __syncthreads();   // weights + range published block-wide

        if (role_build01) {
            const int k = b >> 4;
            const float u0 = rng_s[0], dlt = rng_s[1];
            const float b3 = ib3[k];
            float* __restrict__ tab = ws + WS_TAB + k * G;
            int mr[2];
            h2 uu[2];
            #pragma unroll
            for (int j = 0; j < 2; ++j) {
                mr[j] = (b & 15) * 256 + j * 128 + wv * 32 + l31;
                float u = fmaf((float)mr[j], dlt, u0);
                uu[j] = hpk2(u, u);
            }
            float dz[2];
            mlp2(sh.mlp.W1, sh.mlp.W2, sh.mlp.w0p, sh.mlp.b0p, sh.mlp.w3p,
                 uu, wrow, hf, hfb, b3, zoff, dz);
            #pragma unroll
            for (int j = 0; j < 2; ++j) if (!hfb) tab[mr[j]] = dz[j];
        } else if (role_probe) {
            const float xm = xmM_s[0], xM = xmM_s[1];
            const float b3 = ib3[0];
            // rows: r = e*101 + p (e in {0,1}: xmin/xmax endpoint, p quad pt)
            int rr[2];
            h2 uu[2];
            #pragma unroll
            for (int j = 0; j < 2; ++j) {
                rr[j] = j * 128 + wv * 32 + l31;
                int r = rr[j];
                float xe = (r < 101) ? xm : xM;
                int p = (r < 101) ? r : (r - 101);
                if (p > 100) p = 0;
                float u = (r < 202) ? xe * ws[WS_XSC + p] : 0.f;
                uu[j] = hpk2(u, u);
            }
            float dz[2];
            mlp2(sh.mlp.W1, sh.mlp.W2, sh.mlp.w0p, sh.mlp.b0p, sh.mlp.w3p,
                 uu, wrow, hf, hfb, b3, zoff, dz);
            #pragma unroll
            for (int j = 0; j < 2; ++j) if (!hfb) sh.mlp.g[rr[j]] = dz[j];
            __syncthreads();

            // quadrature at both endpoints -> x2 range -> net-2 table consts
            if (tid < 64) {
                float s0a = 0.f, s1a = 0.f;
                for (int p = tid; p < 101; p += 64) {
                    float c = ws[WS_CCW + p];
                    s0a = fmaf(c, sh.mlp.g[p], s0a);
                    s1a = fmaf(c, sh.mlp.g[101 + p], s1a);
                }
                #pragma unroll
                for (int off = 1; off < 64; off <<= 1) {
                    s0a += __shfl_xor(s0a, off, 64);
                    s1a += __shfl_xor(s1a, off, 64);
                }
                if (tid == 0) {
                    float z0 = 0.5f * xm * s0a;
                    float z1 = 0.5f * xM * s1a;
                    float o0 = ws[WS_OH0 + 0], e1 = ws[WS_EOH1 + 0];
                    float a = fmaf(e1, z0, o0);
                    float bb = fmaf(e1, z1, o0);
                    float x2m = fminf(a, bb), x2M = fmaxf(a, bb);
                    float sp = fmaxf(x2M - x2m, 1e-6f);
                    x2m -= 0.02f * sp;                 // safety margin: quadrature
                    x2M += 0.02f * sp;                 // wiggle + table-lerp error
                    float um = fminf(x2m, 0.f), uM = fmaxf(x2M, 0.f);
                    float span = fmaxf(uM - um, 1e-5f);
                    ws[WS_RNG + 8]  = um;
                    ws[WS_RNG + 9]  = span * (1.f / (float)(G - 1));
                    ws[WS_RNG + 10] = (float)(G - 1) / span;
                }
            }
        }
    }
    gridbar(bar, 1);

    // ---------------- phase C: build table 2 || pre-stage tables 0,1 ----------------
    if (role_stage2) {
        const float u0 = ws[WS_RNG + 8];
        const float dlt = ws[WS_RNG + 9];
        const float b3 = ib3[2];
        float* __restrict__ tab = ws + WS_TAB + 2 * G;
        int mr[2];
        h2 uu[2];
        #pragma unroll
        for (int j = 0; j < 2; ++j) {
            mr[j] = (b & 15) * 256 + j * 128 + wv * 32 + l31;
            float u = fmaf((float)mr[j], dlt, u0);
            uu[j] = hpk2(u, u);
        }
        float dz[2];
        mlp2(sh.mlp.W1, sh.mlp.W2, sh.mlp.w0p, sh.mlp.b0p, sh.mlp.w3p,
             uu, wrow, hf, hfb, b3, zoff, dz);
        #pragma unroll
        for (int j = 0; j < 2; ++j) if (!hfb) tab[mr[j]] = dz[j];
    } else {
        const float* tg = ws + WS_TAB;
        for (int i = tid * 4; i < 2 * G; i += 1024)
            *(float4*)&sh.ev.tab[i] = *(const float4*)&tg[i];
        if (tid < 101) {
            xsc_s[tid] = ws[WS_XSC + tid];
            ccw_s[tid] = ws[WS_CCW + tid];
        }
    }
    gridbar(bar, 2);

    // ---------------- phase D: eval ----------------
    {
        const float* tg = ws + WS_TAB;
        if (role_stage2) {
            for (int i = tid * 4; i < 3 * G; i += 1024)
                *(float4*)&sh.ev.tab[i] = *(const float4*)&tg[i];
            if (tid < 101) {
                xsc_s[tid] = ws[WS_XSC + tid];
                ccw_s[tid] = ws[WS_CCW + tid];
            }
        } else {
            for (int i = 2 * G + tid * 4; i < 3 * G; i += 1024)
                *(float4*)&sh.ev.tab[i] = *(const float4*)&tg[i];
        }
        __syncthreads();

        const float u00 = ws[WS_RNG + 0], iv0v = ws[WS_RNG + 2];
        const float u01 = ws[WS_RNG + 4], iv1v = ws[WS_RNG + 6];
        const float u02 = ws[WS_RNG + 8], iv2v = ws[WS_RNG + 10];
        const float o00 = ws[WS_OH0 + 0], e10 = ws[WS_EOH1 + 0];
        const float o01 = ws[WS_OH0 + 1], e11 = ws[WS_EOH1 + 1];
        const float o02 = ws[WS_OH0 + 2], e12 = ws[WS_EOH1 + 2];
        const int psub = tid & 3;

        for (int nn0 = ibeg; nn0 < iend; nn0 += 64) {
            int nn = nn0 + (tid >> 2);
            bool valid = (nn < iend);
            float x = valid ? logits[nn] : 0.f;

            float z1 = quadz(sh.ev.tab + G, xsc_s, ccw_s, x, u01, iv1v, psub);
            float y1v = fmaf(e11, 0.5f * x * z1, o01);

            float z0 = quadz(sh.ev.tab, xsc_s, ccw_s, x, u00, iv0v, psub);
            float x2 = fmaf(e10, 0.5f * x * z0, o00);

            float z2 = quadz(sh.ev.tab + 2 * G, xsc_s, ccw_s, x2, u02, iv2v, psub);
            float y2v = fmaf(e12, 0.5f * x2 * z2, o02);

            if (valid && psub == 0) {
                out[nn] = y1v;
                out[n + nn] = y2v;
            }
        }
    }
}

extern "C" void kernel_launch(void* const* d_in, const int* in_sizes, int n_in,
                              void* d_out, int out_size, void* d_ws, size_t ws_size,
                              hipStream_t stream)
{
    const float* logits = (const float*)d_in[0];
    const float* iW0 = (const float*)d_in[2];
    const float* ib0 = (const float*)d_in[3];
    const float* iW1 = (const float*)d_in[4];
    const float* ib1 = (const float*)d_in[5];
    const float* iW2 = (const float*)d_in[6];
    const float* ib2 = (const float*)d_in[7];
    const float* iW3 = (const float*)d_in[8];
    const float* ib3 = (const float*)d_in[9];
    const float* hb0 = (const float*)d_in[11];
    const float* hW1 = (const float*)d_in[12];
    const float* hb1 = (const float*)d_in[13];
    const float* hW2 = (const float*)d_in[14];
    const float* hb2 = (const float*)d_in[15];
    const float* hW3 = (const float*)d_in[16];
    const float* hb3 = (const float*)d_in[17];
    float* out = (float*)d_out;
    float* ws = (float*)d_ws;
    int n = in_sizes[0];

    // zero the one-shot grid-barrier counters (captured per-iteration)
    hipMemsetAsync((void*)(ws + WS_BAR), 0, 4 * sizeof(int), stream);

    hipLaunchKernelGGL(mega_kernel, dim3(NBLK), dim3(256), 0, stream,
                       logits, iW0, ib0, iW1, ib1, iW2, ib2, iW3, ib3,
                       hb0, hW1, hb1, hW2, hb2, hW3, hb3, ws, out, n);
}

// Round 6
// 166.983 us; speedup vs baseline: 1.9478x; 1.0668x over previous
//
#include <hip/hip_runtime.h>
#include <hip/hip_bf16.h>
#include <hip/hip_fp16.h>
#include <math.h>

typedef _Float16 f16x8 __attribute__((ext_vector_type(8)));
typedef _Float16 h2 __attribute__((ext_vector_type(2)));
typedef __fp16 h2amd __attribute__((ext_vector_type(2)));   // builtin return type
typedef float f32x16 __attribute__((ext_vector_type(16)));
typedef float f32x2 __attribute__((ext_vector_type(2)));

#define DH 100      // hidden dim
#define G  4096     // table size per net
#define WSTR 120    // LDS row stride in f16 elems
#define NBLK 64     // grid size. R4 post-mortem: barrier cost is O(#blocks)
                    // (wb/inv maintenance ops serialize at the fabric) -> run
                    // the minimum grid that covers the 49 build/probe blocks.
                    // 64 blocks <= 256 CUs => co-residency by capacity alone.

// ws float offsets
#define WS_CCW   0      // [0,101)
#define WS_XSC   128    // [128,229)
#define WS_OH0   256    // 3
#define WS_EOH1  260    // 3
#define WS_P01   264    // NBLK min/max pairs (logits)  [264,392)
#define WS_RNG   800    // 3 nets x {u0, dlt, inv, pad} [800,812)
#define WS_BAR   960    // ints: cnt[0..3] @ +0 (line 30), flags @ +32 (line 31)
#define WS_TAB   17408  // 3*G table floats

__device__ __forceinline__ unsigned short f2bf(float f) {
    unsigned int u = __float_as_uint(f);
    unsigned int r = (u + 0x7FFFu + ((u >> 16) & 1u)) >> 16;  // RNE
    return (unsigned short)r;
}
__device__ __forceinline__ unsigned int hpk(float a, float b) {
    union { h2amd h; unsigned int u; } c;
    c.h = __builtin_amdgcn_cvt_pkrtz(a, b);
    return c.u;
}
__device__ __forceinline__ h2 hpk2(float a, float b) {
    union { h2amd ha; h2 h; } c;
    c.ha = __builtin_amdgcn_cvt_pkrtz(a, b);
    return c.h;
}

// grid barrier v3: arrivals fetch_add a counter (relaxed, agent); the LAST
// arriver stores a release flag on a SEPARATE cacheline; everyone else polls
// that write-once line with relaxed loads (no RMW/poll same-line contention,
// no per-poll cache maintenance). One release fence before arrival, one
// acquire fence after exit, per block. Deadlock-free: grid <= CU count.
// Graph-replay-safe: stale (un-memset) counters/flags fall THROUGH, never hang.
__device__ __forceinline__ void gridbar(int* bar, int idx) {
    __syncthreads();
    if (threadIdx.x == 0) {
        __threadfence();   // release: flush this block's global writes
        int old = __hip_atomic_fetch_add(&bar[idx], 1, __ATOMIC_RELAXED,
                                         __HIP_MEMORY_SCOPE_AGENT);
        if (old == NBLK - 1) {
            __hip_atomic_store(&bar[32 + idx], 1, __ATOMIC_RELAXED,
                               __HIP_MEMORY_SCOPE_AGENT);
        } else {
            while (__hip_atomic_load(&bar[32 + idx], __ATOMIC_RELAXED,
                                     __HIP_MEMORY_SCOPE_AGENT) == 0)
                __builtin_amdgcn_s_sleep(8);
        }
        __threadfence();   // acquire: drop stale cached lines (once)
    }
    __syncthreads();
}

union FR { f16x8 v; h2 h[4]; unsigned int u32[4]; };

// phase-overlaid LDS (max member ~49.8 KB)
union MegaSh {
    struct { float hw[DH * 101]; float bufA[128]; float bufB[128]; } prep;
    struct {
        __align__(16) _Float16 W1[DH * WSTR];
        __align__(16) _Float16 W2[DH * WSTR];
        unsigned int w0p[64], b0p[64], w3p[64];
        float g[256];
    } mlp;
    struct { __align__(16) float tab[3 * G]; } ev;
};

// R3-R11-verified transposed MFMA dataflow (lane^32 exchange, laundered LDS
// reads): evaluates g(u)=elu(MLP(u))+1 for the two 128-row groups. dzout[j]
// is valid on !hfb lanes.
__device__ __forceinline__ void mlp2(const _Float16* __restrict__ W1s,
                                     const _Float16* __restrict__ W2s,
                                     const unsigned int* __restrict__ w0p_s,
                                     const unsigned int* __restrict__ b0p_s,
                                     const unsigned int* __restrict__ w3p_s,
                                     const h2* uu, const int* wrow,
                                     const int hf, const bool hfb,
                                     const float b3, unsigned int zoff,
                                     float* dzout)
{
    const f32x2 zero2 = {0.f, 0.f};

    // layer 1: B-frags for both row groups, shared w0/b0 loads
    FR a1[2][7];
    #pragma unroll
    for (int ks = 0; ks < 7; ++ks) {
        int pb = ks * 8 + hf * 4 + zoff;
        uint4 wq = *(const uint4*)&w0p_s[pb];
        uint4 bq = *(const uint4*)&b0p_s[pb];
        unsigned int wqa[4] = {wq.x, wq.y, wq.z, wq.w};
        unsigned int bqa[4] = {bq.x, bq.y, bq.z, bq.w};
        #pragma unroll
        for (int i = 0; i < 4; ++i) {
            union { unsigned int u; h2 h; } cw, cb;
            cw.u = wqa[i]; cb.u = bqa[i];
            h2 z = {(_Float16)0.f, (_Float16)0.f};
            #pragma unroll
            for (int j = 0; j < 2; ++j) {
                h2 r = __builtin_elementwise_fma(uu[j], cw.h, cb.h);
                a1[j][ks].h[i] = __builtin_elementwise_max(r, z);
            }
        }
    }

    // layer 2: dual accumulators share weight loads; pack+exchange -> f3
    FR f3[2][7];
    #pragma unroll
    for (int nt = 0; nt < 4; ++nt) {
        f32x16 acc[2];
        #pragma unroll
        for (int r = 0; r < 16; ++r) { acc[0][r] = 0.f; acc[1][r] = 0.f; }
        #pragma unroll
        for (int ks = 0; ks < 7; ++ks) {
            f16x8 wA = *(const f16x8*)&W1s[wrow[nt] + ks * 16 + zoff];
            acc[0] = __builtin_amdgcn_mfma_f32_32x32x16_f16(wA, a1[0][ks].v, acc[0], 0, 0, 0);
            acc[1] = __builtin_amdgcn_mfma_f32_32x32x16_f16(wA, a1[1][ks].v, acc[1], 0, 0, 0);
        }
        #pragma unroll
        for (int j = 0; j < 2; ++j) {
            if (nt < 3) {
                unsigned int pk[4][2];
                #pragma unroll
                for (int qi = 0; qi < 4; ++qi) {
                    f32x2 lo = {acc[j][4 * qi + 0], acc[j][4 * qi + 1]};
                    f32x2 hi = {acc[j][4 * qi + 2], acc[j][4 * qi + 3]};
                    lo = __builtin_elementwise_max(lo, zero2);
                    hi = __builtin_elementwise_max(hi, zero2);
                    pk[qi][0] = hpk(lo[0], lo[1]);
                    pk[qi][1] = hpk(hi[0], hi[1]);
                }
                #pragma unroll
                for (int kk = 0; kk < 2; ++kk) {
                    unsigned int X0 = hfb ? pk[2 * kk][0] : pk[2 * kk + 1][0];
                    unsigned int X1 = hfb ? pk[2 * kk][1] : pk[2 * kk + 1][1];
                    unsigned int O0 = hfb ? pk[2 * kk + 1][0] : pk[2 * kk][0];
                    unsigned int O1 = hfb ? pk[2 * kk + 1][1] : pk[2 * kk][1];
                    unsigned int Y0 = (unsigned int)__shfl_xor((int)X0, 32, 64);
                    unsigned int Y1 = (unsigned int)__shfl_xor((int)X1, 32, 64);
                    f3[j][nt * 2 + kk].u32[0] = hfb ? Y0 : O0;
                    f3[j][nt * 2 + kk].u32[1] = hfb ? Y1 : O1;
                    f3[j][nt * 2 + kk].u32[2] = hfb ? O0 : Y0;
                    f3[j][nt * 2 + kk].u32[3] = hfb ? O1 : Y1;
                }
            } else {
                f32x2 lo = {acc[j][0], acc[j][1]};
                f32x2 hi = {acc[j][2], acc[j][3]};
                lo = __builtin_elementwise_max(lo, zero2);
                hi = __builtin_elementwise_max(hi, zero2);
                unsigned int p0 = hpk(lo[0], lo[1]);
                unsigned int p1 = hpk(hi[0], hi[1]);
                f3[j][6].u32[0] = hfb ? 0u : p0;
                f3[j][6].u32[1] = hfb ? 0u : p1;
                f3[j][6].u32[2] = hfb ? 0u : 0x00003C00u;   // f16 1.0 (bias slot)
                f3[j][6].u32[3] = 0u;
            }
        }
    }

    // layer 3: dual accumulators; shared W2 + w3 loads; fold w3
    f32x2 oacc2[2] = {{0.f, 0.f}, {0.f, 0.f}};
    #pragma unroll
    for (int nt2 = 0; nt2 < 4; ++nt2) {
        f32x16 acc2[2];
        #pragma unroll
        for (int r = 0; r < 16; ++r) { acc2[0][r] = 0.f; acc2[1][r] = 0.f; }
        #pragma unroll
        for (int ks = 0; ks < 7; ++ks) {
            f16x8 wA = *(const f16x8*)&W2s[wrow[nt2] + ks * 16 + zoff];
            acc2[0] = __builtin_amdgcn_mfma_f32_32x32x16_f16(wA, f3[0][ks].v, acc2[0], 0, 0, 0);
            acc2[1] = __builtin_amdgcn_mfma_f32_32x32x16_f16(wA, f3[1][ks].v, acc2[1], 0, 0, 0);
        }
        uint4 wa = *(const uint4*)&w3p_s[hf * 32 + nt2 * 8 + zoff];
        uint4 wb2 = *(const uint4*)&w3p_s[hf * 32 + nt2 * 8 + 4 + zoff];
        unsigned int w8[8] = {wa.x, wa.y, wa.z, wa.w, wb2.x, wb2.y, wb2.z, wb2.w};
        f32x2 w3v[8];
        #pragma unroll
        for (int q = 0; q < 8; ++q) {
            w3v[q][0] = __uint_as_float(w8[q] << 16);
            w3v[q][1] = __uint_as_float(w8[q] & 0xFFFF0000u);
        }
        #pragma unroll
        for (int j = 0; j < 2; ++j)
            #pragma unroll
            for (int qi = 0; qi < 4; ++qi) {
                f32x2 lo = {acc2[j][4 * qi + 0], acc2[j][4 * qi + 1]};
                f32x2 hi = {acc2[j][4 * qi + 2], acc2[j][4 * qi + 3]};
                lo = __builtin_elementwise_max(lo, zero2);
                hi = __builtin_elementwise_max(hi, zero2);
                oacc2[j] = __builtin_elementwise_fma(lo, w3v[qi * 2], oacc2[j]);
                oacc2[j] = __builtin_elementwise_fma(hi, w3v[qi * 2 + 1], oacc2[j]);
            }
    }

    #pragma unroll
    for (int j = 0; j < 2; ++j) {
        float oacc = oacc2[j][0] + oacc2[j][1];
        float o = oacc + __shfl_xor(oacc, 32, 64) + b3;
        dzout[j] = (o > 0.f) ? (o + 1.f) : expf(o);   // elu(o) + 1
    }
}

// quadrature of one net's table: z = sum_p ccw[p] * lerp(tab, x*xsc[p]),
// 4 threads/sample (point-strided), butterfly reduce over the 4-lane group.
__device__ __forceinline__ float quadz(const float* __restrict__ tab_s,
                                       const float* __restrict__ xsc_s,
                                       const float* __restrict__ ccw_s,
                                       float x, float u0, float invd, int psub)
{
    float z = 0.f;
    for (int p = psub; p < 101; p += 4) {
        float u = x * xsc_s[p];
        float tt = fminf(fmaxf((u - u0) * invd, 0.f), (float)(G - 1) - 0.001f);
        int i = (int)tt;
        float f = tt - (float)i;
        float g0 = tab_s[i];
        float g1 = tab_s[i + 1];
        z = fmaf(ccw_s[p], fmaf(f, g1 - g0, g0), z);
    }
    z += __shfl_xor(z, 1, 64);
    z += __shfl_xor(z, 2, 64);
    return z;
}

// Single kernel, 2 grid barriers + 1 producer/consumer flag:
//  A: passthrough + minmax partials (all), h-MLP (blocks 0-2), CC consts (block 3)
//  B: build tables 0,1 (blocks 0-31) || probe (block 48) -> flag ->
//     build table 2 (blocks 32-47, poll flag)
//  D: stage all 3 tables, eval y1 + register-chained x2->y2 (all blocks)
__global__ __launch_bounds__(256, 2)
void mega_kernel(const float* __restrict__ logits,
                 const float* __restrict__ iW0, const float* __restrict__ ib0,
                 const float* __restrict__ iW1, const float* __restrict__ ib1,
                 const float* __restrict__ iW2, const float* __restrict__ ib2,
                 const float* __restrict__ iW3, const float* __restrict__ ib3,
                 const float* __restrict__ hb0,
                 const float* __restrict__ hW1, const float* __restrict__ hb1,
                 const float* __restrict__ hW2, const float* __restrict__ hb2,
                 const float* __restrict__ hW3, const float* __restrict__ hb3,
                 float* __restrict__ ws, float* __restrict__ out, int n)
{
    __shared__ MegaSh sh;
    __shared__ float xsc_s[104], ccw_s[104];
    __shared__ float rmin_s[4], rmax_s[4];
    __shared__ float xmM_s[2];
    __shared__ float rng_s[2];      // this block's build {u0, dlt}

    int* bar = (int*)(ws + WS_BAR);
    const int tid = threadIdx.x;
    const int b = blockIdx.x;
    const int lane = tid & 63;
    const int wv = tid >> 6;
    const int hf = lane >> 5;
    const bool hfb = (hf != 0);
    const int l31 = lane & 31;
    const int spb = (n + NBLK - 1) / NBLK;      // 256 at n=16384
    const int ibeg = b * spb;
    const int iend = (ibeg + spb < n) ? (ibeg + spb) : n;

    // ---------------- phase A ----------------
    {
        float lmin = 1e30f, lmax = -1e30f;
        for (int i = ibeg + tid; i < iend; i += 256) {
            float v = logits[i];
            out[2 * n + i] = v;
            lmin = fminf(lmin, v);
            lmax = fmaxf(lmax, v);
        }
        #pragma unroll
        for (int off = 1; off < 64; off <<= 1) {
            lmin = fminf(lmin, __shfl_xor(lmin, off, 64));
            lmax = fmaxf(lmax, __shfl_xor(lmax, off, 64));
        }
        if (lane == 0) { rmin_s[wv] = lmin; rmax_s[wv] = lmax; }
    }
    __syncthreads();
    if (tid == 0) {
        ws[WS_P01 + 2 * b]     = fminf(fminf(rmin_s[0], rmin_s[1]), fminf(rmin_s[2], rmin_s[3]));
        ws[WS_P01 + 2 * b + 1] = fmaxf(fmaxf(rmax_s[0], rmax_s[1]), fmaxf(rmax_s[2], rmax_s[3]));
    }

    if (b == 3) {
        // CC quadrature consts. cos(j*t*pi/100) has period 200 in (j*t):
        // exact integer reduction, then small-arg cosf (f32 error ~1e-6 on
        // weights of O(0.02) -> negligible vs 0.084 threshold).
        if (tid <= 100) {
            const int t = tid;
            float ccw = 0.f;
            for (int j = 0; j <= 100; j += 2) {
                float wj = (j == 0) ? 1.f : 2.f / (1.f - (float)(j * j));
                float lam;
                if (t == 0) lam = 0.5f;
                else {
                    int r = (j * t) % 200;
                    lam = cosf((float)r * 0.031415926535f);   // r*pi/100
                    if (t == 100) lam *= 0.5f;
                }
                ccw = fmaf(lam * wj, 0.02f, ccw);
            }
            ws[WS_CCW + tid] = ccw;
            ws[WS_XSC + tid] = (cosf((float)t * 0.031415926535f) + 1.f) * 0.5f;
        }
    } else if (b < 3) {
        const int k = b;                       // one net per block
        if (tid < 128) sh.prep.bufA[tid] = (tid < DH) ? fmaxf(hb0[k * DH + tid], 0.f) : 0.f;
        __syncthreads();
        for (int i = tid; i < DH * DH; i += 256) {
            int r = i / DH, c = i - r * DH;
            sh.prep.hw[r * 101 + c] = hW1[k * DH * DH + i];
        }
        __syncthreads();
        if (tid < DH) {
            float acc = hb1[k * DH + tid];
            for (int i = 0; i < DH; ++i) acc = fmaf(sh.prep.hw[tid * 101 + i], sh.prep.bufA[i], acc);
            sh.prep.bufB[tid] = fmaxf(acc, 0.f);
        }
        __syncthreads();
        for (int i = tid; i < DH * DH; i += 256) {
            int r = i / DH, c = i - r * DH;
            sh.prep.hw[r * 101 + c] = hW2[k * DH * DH + i];
        }
        __syncthreads();
        if (tid < DH) {
            float acc = hb2[k * DH + tid];
            for (int i = 0; i < DH; ++i) acc = fmaf(sh.prep.hw[tid * 101 + i], sh.prep.bufB[i], acc);
            sh.prep.bufA[tid] = fmaxf(acc, 0.f);
        }
        __syncthreads();
        if (tid < 2) {
            float acc = hb3[k * 2 + tid];
            const float* w = hW3 + (size_t)(k * 2 + tid) * DH;
            for (int i = 0; i < DH; ++i) acc = fmaf(w[i], sh.prep.bufA[i], acc);
            if (tid == 0) ws[WS_OH0 + k] = acc;
            else          ws[WS_EOH1 + k] = expf(acc);
        }
    }
    gridbar(bar, 0);

    // ---------------- phase B: builds + probe, flag-chained ----------------
    unsigned int zoff = 0;
    asm volatile("" : "+v"(zoff));   // opaque zero (keeps LDS reads un-cached)

    int wrow[4];
    #pragma unroll
    for (int nt = 0; nt < 4; ++nt) {
        int r = nt * 32 + l31;
        wrow[nt] = ((r > DH - 1) ? (DH - 1) : r) * WSTR + hf * 8;
    }

    if (b < 49) {
        const bool role_probe = (b == 48);
        const int kk = role_probe ? 0 : (b >> 4);
        if (tid < 64) {
            int s0 = 2 * tid, s1 = 2 * tid + 1;
            float w0a = (s0 < DH) ? iW0[(kk * DH + s0) * 3] : 0.f;   // h==0: feature 0 only
            float w0b = (s1 < DH) ? iW0[(kk * DH + s1) * 3] : 0.f;
            float b0a = (s0 < DH) ? ib0[kk * DH + s0] : ((s0 == DH) ? 1.f : 0.f);
            float b0b = (s1 < DH) ? ib0[kk * DH + s1] : 0.f;
            sh.mlp.w0p[tid] = hpk(w0a, w0b);
            sh.mlp.b0p[tid] = hpk(b0a, b0b);

            int hf_i = tid >> 5, rem = tid & 31;
            int nt2 = rem >> 3, qq = (rem >> 1) & 3, pr = rem & 1;
            int n2e = 32 * nt2 + 8 * qq + 2 * pr + 4 * hf_i;
            float we = (n2e < DH) ? iW3[kk * DH + n2e] : 0.f;
            float wo = (n2e + 1 < DH) ? iW3[kk * DH + n2e + 1] : 0.f;
            sh.mlp.w3p[tid] = ((unsigned int)f2bf(wo) << 16) | (unsigned int)f2bf(we);

            // every staging/probing block reduces the logits range itself
            float pm = 1e30f, pM = -1e30f;
            for (int i = tid; i < NBLK; i += 64) {
                pm = fminf(pm, ws[WS_P01 + 2 * i]);
                pM = fmaxf(pM, ws[WS_P01 + 2 * i + 1]);
            }
            #pragma unroll
            for (int off = 1; off < 64; off <<= 1) {
                pm = fminf(pm, __shfl_xor(pm, off, 64));
                pM = fmaxf(pM, __shfl_xor(pM, off, 64));
            }
            if (tid == 0) {
                float um = fminf(pm, 0.f), uM = fmaxf(pM, 0.f);
                float span = fmaxf(uM - um, 1e-5f);
                float d = span * (1.f / (float)(G - 1));
                float iv = (float)(G - 1) / span;
                rng_s[0] = um; rng_s[1] = d;
                xmM_s[0] = pm; xmM_s[1] = pM;
                if (role_probe) {
                    ws[WS_RNG + 0] = um; ws[WS_RNG + 1] = d; ws[WS_RNG + 2] = iv;   // net 0
                    ws[WS_RNG + 4] = um; ws[WS_RNG + 5] = d; ws[WS_RNG + 6] = iv;   // net 1
                }
            }
        }
        const float* W1g = iW1 + (size_t)kk * DH * DH;
        const float* W2g = iW2 + (size_t)kk * DH * DH;
        for (int i = tid; i < DH * WSTR; i += 256) {
            int r = i / WSTR, c = i - r * WSTR;
            float v1, v2;
            if (c < DH)       { v1 = W1g[r * DH + c]; v2 = W2g[r * DH + c]; }
            else if (c == DH) { v1 = ib1[kk * DH + r]; v2 = ib2[kk * DH + r]; }
            else              { v1 = 0.f; v2 = 0.f; }
            sh.mlp.W1[r * WSTR + c] = (_Float16)v1;
            sh.mlp.W2[r * WSTR + c] = (_Float16)v2;
        }
        __syncthreads();   // weights + range published block-wide

        if (b < 32) {
            // build tables 0,1 over the logits-derived range
            const int k = b >> 4;
            const float u0 = rng_s[0], dlt = rng_s[1];
            const float b3 = ib3[k];
            float* __restrict__ tab = ws + WS_TAB + k * G;
            int mr[2];
            h2 uu[2];
            #pragma unroll
            for (int j = 0; j < 2; ++j) {
                mr[j] = (b & 15) * 256 + j * 128 + wv * 32 + l31;
                float u = fmaf((float)mr[j], dlt, u0);
                uu[j] = hpk2(u, u);
            }
            float dz[2];
            mlp2(sh.mlp.W1, sh.mlp.W2, sh.mlp.w0p, sh.mlp.b0p, sh.mlp.w3p,
                 uu, wrow, hf, hfb, b3, zoff, dz);
            #pragma unroll
            for (int j = 0; j < 2; ++j) if (!hfb) tab[mr[j]] = dz[j];
        } else if (role_probe) {
            const float xm = xmM_s[0], xM = xmM_s[1];
            const float b3 = ib3[0];
            // rows: r = e*101 + p (e in {0,1}: xmin/xmax endpoint, p quad pt)
            int rr[2];
            h2 uu[2];
            #pragma unroll
            for (int j = 0; j < 2; ++j) {
                rr[j] = j * 128 + wv * 32 + l31;
                int r = rr[j];
                float xe = (r < 101) ? xm : xM;
                int p = (r < 101) ? r : (r - 101);
                if (p > 100) p = 0;
                float u = (r < 202) ? xe * ws[WS_XSC + p] : 0.f;
                uu[j] = hpk2(u, u);
            }
            float dz[2];
            mlp2(sh.mlp.W1, sh.mlp.W2, sh.mlp.w0p, sh.mlp.b0p, sh.mlp.w3p,
                 uu, wrow, hf, hfb, b3, zoff, dz);
            #pragma unroll
            for (int j = 0; j < 2; ++j) if (!hfb) sh.mlp.g[rr[j]] = dz[j];
            __syncthreads();

            // quadrature at both endpoints -> x2 range -> net-2 table consts
            if (tid < 64) {
                float s0a = 0.f, s1a = 0.f;
                for (int p = tid; p < 101; p += 64) {
                    float c = ws[WS_CCW + p];
                    s0a = fmaf(c, sh.mlp.g[p], s0a);
                    s1a = fmaf(c, sh.mlp.g[101 + p], s1a);
                }
                #pragma unroll
                for (int off = 1; off < 64; off <<= 1) {
                    s0a += __shfl_xor(s0a, off, 64);
                    s1a += __shfl_xor(s1a, off, 64);
                }
                if (tid == 0) {
                    float z0 = 0.5f * xm * s0a;
                    float z1 = 0.5f * xM * s1a;
                    float o0 = ws[WS_OH0 + 0], e1 = ws[WS_EOH1 + 0];
                    float a = fmaf(e1, z0, o0);
                    float bb = fmaf(e1, z1, o0);
                    float x2m = fminf(a, bb), x2M = fmaxf(a, bb);
                    float sp = fmaxf(x2M - x2m, 1e-6f);
                    x2m -= 0.02f * sp;                 // safety margin: quadrature
                    x2M += 0.02f * sp;                 // wiggle + table-lerp error
                    float um = fminf(x2m, 0.f), uM = fmaxf(x2M, 0.f);
                    float span = fmaxf(uM - um, 1e-5f);
                    ws[WS_RNG + 8]  = um;
                    ws[WS_RNG + 9]  = span * (1.f / (float)(G - 1));
                    ws[WS_RNG + 10] = (float)(G - 1) / span;
                    __threadfence();   // release WS_RNG[8..10]
                    __hip_atomic_store(&bar[35], 1, __ATOMIC_RELAXED,
                                       __HIP_MEMORY_SCOPE_AGENT);
                }
            }
        } else {
            // blocks 32-47: wait on the probe flag, then build table 2
            if (tid == 0) {
                while (__hip_atomic_load(&bar[35], __ATOMIC_RELAXED,
                                         __HIP_MEMORY_SCOPE_AGENT) == 0)
                    __builtin_amdgcn_s_sleep(4);
                __threadfence();   // acquire WS_RNG[8..10]
            }
            __syncthreads();
            const float u0 = ws[WS_RNG + 8];
            const float dlt = ws[WS_RNG + 9];
            const float b3 = ib3[2];
            float* __restrict__ tab = ws + WS_TAB + 2 * G;
            int mr[2];
            h2 uu[2];
            #pragma unroll
            for (int j = 0; j < 2; ++j) {
                mr[j] = (b & 15) * 256 + j * 128 + wv * 32 + l31;
                float u = fmaf((float)mr[j], dlt, u0);
                uu[j] = hpk2(u, u);
            }
            float dz[2];
            mlp2(sh.mlp.W1, sh.mlp.W2, sh.mlp.w0p, sh.mlp.b0p, sh.mlp.w3p,
                 uu, wrow, hf, hfb, b3, zoff, dz);
            #pragma unroll
            for (int j = 0; j < 2; ++j) if (!hfb) tab[mr[j]] = dz[j];
        }
    }
    gridbar(bar, 1);

    // ---------------- phase D: eval ----------------
    {
        const float* tg = ws + WS_TAB;
        for (int i = tid * 4; i < 3 * G; i += 1024)
            *(float4*)&sh.ev.tab[i] = *(const float4*)&tg[i];
        if (tid < 101) {
            xsc_s[tid] = ws[WS_XSC + tid];
            ccw_s[tid] = ws[WS_CCW + tid];
        }
        __syncthreads();

        const float u00 = ws[WS_RNG + 0], iv0v = ws[WS_RNG + 2];
        const float u01 = ws[WS_RNG + 4], iv1v = ws[WS_RNG + 6];
        const float u02 = ws[WS_RNG + 8], iv2v = ws[WS_RNG + 10];
        const float o00 = ws[WS_OH0 + 0], e10 = ws[WS_EOH1 + 0];
        const float o01 = ws[WS_OH0 + 1], e11 = ws[WS_EOH1 + 1];
        const float o02 = ws[WS_OH0 + 2], e12 = ws[WS_EOH1 + 2];
        const int psub = tid & 3;

        for (int nn0 = ibeg; nn0 < iend; nn0 += 64) {
            int nn = nn0 + (tid >> 2);
            bool valid = (nn < iend);
            float x = valid ? logits[nn] : 0.f;

            float z1 = quadz(sh.ev.tab + G, xsc_s, ccw_s, x, u01, iv1v, psub);
            float y1v = fmaf(e11, 0.5f * x * z1, o01);

            float z0 = quadz(sh.ev.tab, xsc_s, ccw_s, x, u00, iv0v, psub);
            float x2 = fmaf(e10, 0.5f * x * z0, o00);

            float z2 = quadz(sh.ev.tab + 2 * G, xsc_s, ccw_s, x2, u02, iv2v, psub);
            float y2v = fmaf(e12, 0.5f * x2 * z2, o02);

            if (valid && psub == 0) {
                out[nn] = y1v;
                out[n + nn] = y2v;
            }
        }
    }
}

extern "C" void kernel_launch(void* const* d_in, const int* in_sizes, int n_in,
                              void* d_out, int out_size, void* d_ws, size_t ws_size,
                              hipStream_t stream)
{
    const float* logits = (const float*)d_in[0];
    const float* iW0 = (const float*)d_in[2];
    const float* ib0 = (const float*)d_in[3];
    const float* iW1 = (const float*)d_in[4];
    const float* ib1 = (const float*)d_in[5];
    const float* iW2 = (const float*)d_in[6];
    const float* ib2 = (const float*)d_in[7];
    const float* iW3 = (const float*)d_in[8];
    const float* ib3 = (const float*)d_in[9];
    const float* hb0 = (const float*)d_in[11];
    const float* hW1 = (const float*)d_in[12];
    const float* hb1 = (const float*)d_in[13];
    const float* hW2 = (const float*)d_in[14];
    const float* hb2 = (const float*)d_in[15];
    const float* hW3 = (const float*)d_in[16];
    const float* hb3 = (const float*)d_in[17];
    float* out = (float*)d_out;
    float* ws = (float*)d_ws;
    int n = in_sizes[0];

    // zero the barrier counters + flags (captured per-iteration)
    hipMemsetAsync((void*)(ws + WS_BAR), 0, 40 * sizeof(int), stream);

    hipLaunchKernelGGL(mega_kernel, dim3(NBLK), dim3(256), 0, stream,
                       logits, iW0, ib0, iW1, ib1, iW2, ib2, iW3, ib3,
                       hb0, hW1, hb1, hW2, hb2, hW3, hb3, ws, out, n);
}